// Round 2
// baseline (632.979 us; speedup 1.0000x reference)
//
#include <hip/hip_runtime.h>
#include <hip/hip_bf16.h>

#define NROWS 131072
#define D     256
#define NC    512
#define RPB   32
#define KC    16
#define NBLK  (NROWS / RPB)   // 4096

// out layout (fp32 elements), reference return order
#define OFF_ZQ   0L
#define OFF_VQ   33554432L
#define OFF_CM   33554433L
#define OFF_IDX  33554434L
#define OFF_HIST 33685506L

// ws layout (f32): [0]=loss sum, [1..513)=hist, [513..1025)=e^2 norms

__global__ void vq_init(float* __restrict__ ws) {
    int t = threadIdx.x;
    if (t < 513) ws[t] = 0.0f;
}

__global__ void vq_e2(const float* __restrict__ e, float* __restrict__ e2) {
    int c = blockIdx.x;
    int l = threadIdx.x;  // 64 threads
    float4 v = *(const float4*)(e + c * D + l * 4);
    float s = v.x * v.x + v.y * v.y + v.z * v.z + v.w * v.w;
    #pragma unroll
    for (int off = 32; off; off >>= 1) s += __shfl_xor(s, off);
    if (l == 0) e2[c] = s;
}

__global__ __launch_bounds__(256, 2)
void vq_main(const float* __restrict__ z, const float* __restrict__ e,
             const float* __restrict__ e2, float* __restrict__ out,
             float* __restrict__ ws_loss, float* __restrict__ ws_hist) {
    __shared__ __align__(16) float z_s[RPB][D];       // 32 KB, lives through epilogue
    __shared__ __align__(16) float e_s[KC][NC + 4];   // ~33 KB, transposed slab, +4 pad
    __shared__ int   idx_s[RPB];
    __shared__ float red_s[4];

    const int tid  = threadIdx.x;
    const int lane = tid & 63;
    const int w    = tid >> 6;
    const long row0 = (long)blockIdx.x * RPB;

    // ---- stage z tile (contiguous 32 KB, coalesced float4) ----
    {
        const float4* zg = (const float4*)(z + row0 * D);
        float4* zs = (float4*)(&z_s[0][0]);
        #pragma unroll
        for (int i = 0; i < 8; ++i) zs[i * 256 + tid] = zg[i * 256 + tid];
    }

    float acc[8][8];
    #pragma unroll
    for (int r = 0; r < 8; ++r)
        #pragma unroll
        for (int c = 0; c < 8; ++c) acc[r][c] = 0.0f;

    const int r0   = w * 8;        // 8 rows per wave
    const int c_lo = lane * 4;     // lane's cols: c_lo..c_lo+3 and +256

    for (int kc = 0; kc < D; kc += KC) {
        __syncthreads();  // protect e_s against previous iteration's readers (also covers z_s staging)
        // stage e[:, kc:kc+KC] transposed -> e_s[kk][code]
        #pragma unroll
        for (int p = 0; p < 8; ++p) {
            int c   = p * 64 + (tid >> 2);
            int kk4 = (tid & 3) * 4;
            float4 v = *(const float4*)(e + c * D + kc + kk4);
            e_s[kk4 + 0][c] = v.x;
            e_s[kk4 + 1][c] = v.y;
            e_s[kk4 + 2][c] = v.z;
            e_s[kk4 + 3][c] = v.w;
        }
        __syncthreads();
        #pragma unroll
        for (int k4 = 0; k4 < KC; k4 += 4) {
            float zr[8][4];
            #pragma unroll
            for (int r = 0; r < 8; ++r)   // wave-uniform b128 broadcast reads
                *(float4*)zr[r] = *(const float4*)&z_s[r0 + r][kc + k4];
            #pragma unroll
            for (int kk = 0; kk < 4; ++kk) {
                float ev[8];
                *(float4*)&ev[0] = *(const float4*)&e_s[k4 + kk][c_lo];
                *(float4*)&ev[4] = *(const float4*)&e_s[k4 + kk][c_lo + 256];
                #pragma unroll
                for (int r = 0; r < 8; ++r)
                    #pragma unroll
                    for (int c = 0; c < 8; ++c)
                        acc[r][c] = fmaf(zr[r][kk], ev[c], acc[r][c]);
            }
        }
    }

    // ---- argmax epilogue: v = ||e||^2 - 2 z.e  (||z||^2 row-constant, dropped) ----
    float e2v[8];
    #pragma unroll
    for (int g = 0; g < 2; ++g)
        #pragma unroll
        for (int i = 0; i < 4; ++i) e2v[g * 4 + i] = e2[g * 256 + c_lo + i];

    #pragma unroll
    for (int r = 0; r < 8; ++r) {
        float bv = -3.0e38f;
        int   bc = 0;
        #pragma unroll
        for (int c = 0; c < 8; ++c) {   // increasing col order within lane
            int col = (c >> 2) * 256 + c_lo + (c & 3);
            float v = e2v[c] - 2.0f * acc[r][c];
            if (v > bv) { bv = v; bc = col; }
        }
        #pragma unroll
        for (int off = 32; off; off >>= 1) {  // 64-lane butterfly, tie -> lower col
            float ov = __shfl_xor(bv, off);
            int   oc = __shfl_xor(bc, off);
            if (ov > bv || (ov == bv && oc < bc)) { bv = ov; bc = oc; }
        }
        if (lane == 0) idx_s[r0 + r] = bc;
    }
    __syncthreads();

    // idx out (fp32 value) + hist accumulation in f32 ws
    if (tid < RPB) {
        int bc = idx_s[tid];
        out[OFF_IDX + row0 + tid] = (float)bc;
        atomicAdd(&ws_hist[bc], 1.0f);
    }

    // ---- z_q gather + straight-through + elementwise loss (z still in LDS) ----
    float lsum = 0.0f;
    for (int r = 0; r < RPB; ++r) {
        int idx = idx_s[r];
        float ev = e[idx * D + tid];      // coalesced, L2-resident
        float zv = z_s[r][tid];
        float dq = ev - zv;               // z_q - z
        out[OFF_ZQ + (row0 + r) * D + tid] = zv + dq;  // z + (z_q - z)
        lsum += dq * dq;
    }
    #pragma unroll
    for (int off = 32; off; off >>= 1) lsum += __shfl_xor(lsum, off);
    if (lane == 0) red_s[w] = lsum;
    __syncthreads();
    if (tid == 0)
        atomicAdd(ws_loss, red_s[0] + red_s[1] + red_s[2] + red_s[3]);
}

__global__ void vq_fin(const float* __restrict__ ws, float* __restrict__ out) {
    int t = blockIdx.x * blockDim.x + threadIdx.x;
    if (t < NC) out[OFF_HIST + t] = ws[1 + t];
    if (t == NC) {
        float m = ws[0] / 33554432.0f;    // mean((z_q - z)^2)
        out[OFF_VQ] = m;
        out[OFF_CM] = 0.25f * m;
    }
}

extern "C" void kernel_launch(void* const* d_in, const int* in_sizes, int n_in,
                              void* d_out, int out_size, void* d_ws, size_t ws_size,
                              hipStream_t stream) {
    const float* z = (const float*)d_in[0];
    const float* e = (const float*)d_in[1];
    float* out     = (float*)d_out;
    float* ws      = (float*)d_ws;
    float* ws_loss = ws;        // [0]
    float* ws_hist = ws + 1;    // [1..513)
    float* ws_e2   = ws + 513;  // [513..1025)

    vq_init<<<1, 1024, 0, stream>>>(ws);
    vq_e2<<<NC, 64, 0, stream>>>(e, ws_e2);
    vq_main<<<NBLK, 256, 0, stream>>>(z, e, ws_e2, out, ws_loss, ws_hist);
    vq_fin<<<3, 256, 0, stream>>>(ws, out);
}